// Round 1
// baseline (167.543 us; speedup 1.0000x reference)
//
#include <hip/hip_runtime.h>

// Problem constants
#define HGT 256
#define WID 256
#define CH  64
#define NB  2
#define NODES (NB * HGT * WID)
#define NEG_SLOPE 0.2f

// ---------------------------------------------------------------------------
// Kernel A: hfeat = (x + pe) @ lin_w ; a_src = hfeat@att_src ; a_dst = hfeat@att_dst
// pe@lin_w decomposes as py[i]*W0 + px[j]*W1 + Bc (rank-2 + const), computed per block.
// One thread per pixel (j), one block per (b,i) row. 64 fp32 accumulators/thread.
// lin_w accessed with wave-uniform indices -> compiler emits scalar loads + SGPR-FMA.
// ---------------------------------------------------------------------------
__global__ __launch_bounds__(256) void gat_feat(
    const float* __restrict__ x, const float* __restrict__ pos_w,
    const float* __restrict__ pos_b, const float* __restrict__ lin_w,
    const float* __restrict__ att_src, const float* __restrict__ att_dst,
    float* __restrict__ hfeat, float* __restrict__ asrc, float* __restrict__ adst)
{
    __shared__ float W0[CH], W1[CH], Bc[CH];
    const int j  = threadIdx.x;
    const int bi = blockIdx.x;        // = b*HGT + i
    const int i  = bi & (HGT - 1);
    const int b  = bi >> 8;

    if (j < CH) {
        float w0 = 0.f, w1 = 0.f, bc = 0.f;
        for (int ci = 0; ci < CH; ++ci) {
            float lw = lin_w[ci * CH + j];
            w0 = fmaf(pos_w[ci],      lw, w0);   // pos_w[0, ci]
            w1 = fmaf(pos_w[CH + ci], lw, w1);   // pos_w[1, ci]
            bc = fmaf(pos_b[ci],      lw, bc);
        }
        W0[j] = w0; W1[j] = w1; Bc[j] = bc;
    }
    __syncthreads();

    float acc[CH];
    #pragma unroll
    for (int co = 0; co < CH; ++co) acc[co] = 0.f;

    const float* xb = x + ((size_t)b * CH * (HGT * WID) + (size_t)i * WID + j);
    #pragma unroll 4
    for (int ci = 0; ci < CH; ++ci) {
        float xv = xb[(size_t)ci * (HGT * WID)];
        const float* lwr = lin_w + ci * CH;      // wave-uniform row
        #pragma unroll
        for (int co = 0; co < CH; ++co)
            acc[co] = fmaf(xv, lwr[co], acc[co]);
    }

    const float py = -1.f + (2.f / 255.f) * (float)i;
    const float px = -1.f + (2.f / 255.f) * (float)j;

    float as = 0.f, ad = 0.f;
    const size_t node = (size_t)bi * WID + j;    // b*H*W + i*W + j
    float* hrow = hfeat + node * CH;

    #pragma unroll
    for (int co = 0; co < CH; ++co) {
        float h = acc[co] + py * W0[co] + px * W1[co] + Bc[co];
        acc[co] = h;
        as = fmaf(h, att_src[co], as);
        ad = fmaf(h, att_dst[co], ad);
    }
    #pragma unroll
    for (int k = 0; k < CH / 4; ++k) {
        float4 v = make_float4(acc[4*k], acc[4*k+1], acc[4*k+2], acc[4*k+3]);
        reinterpret_cast<float4*>(hrow)[k] = v;
    }
    asrc[node] = as;
    adst[node] = ad;
}

// ---------------------------------------------------------------------------
// Kernel B: per destination pixel, softmax over <=9 valid neighbor taps, then
// out[b,co,i,j] = sum_k alpha_k * hfeat[nbr_k, co] + bias[co].
// ---------------------------------------------------------------------------
__global__ __launch_bounds__(256) void gat_aggr(
    const float* __restrict__ hfeat, const float* __restrict__ asrc,
    const float* __restrict__ adst, const float* __restrict__ bias,
    float* __restrict__ out)
{
    const int j  = threadIdx.x;
    const int bi = blockIdx.x;        // = b*HGT + i
    const int i  = bi & (HGT - 1);
    const int b  = bi >> 8;
    const size_t node = (size_t)bi * WID + j;

    const float ad = adst[node];

    float e[9];
    int   nbr[9];
    float m = -1e30f;
    #pragma unroll
    for (int t = 0; t < 9; ++t) {
        const int dr = t / 3 - 1, dc = t % 3 - 1;
        const int r = i + dr, c = j + dc;
        const bool ok = (r >= 0) && (r < HGT) && (c >= 0) && (c < WID);
        const int nn = (b * HGT + r) * WID + c;
        nbr[t] = ok ? nn : -1;
        float ev = -1e30f;
        if (ok) {
            ev = asrc[nn] + ad;
            ev = (ev >= 0.f) ? ev : NEG_SLOPE * ev;
        }
        e[t] = ev;
        m = fmaxf(m, ev);
    }

    float s = 0.f;
    #pragma unroll
    for (int t = 0; t < 9; ++t) {
        float p = (nbr[t] >= 0) ? __expf(e[t] - m) : 0.f;
        e[t] = p;
        s += p;
    }
    const float inv = 1.f / s;

    float acc[CH];
    #pragma unroll
    for (int co = 0; co < CH; ++co) acc[co] = 0.f;

    #pragma unroll
    for (int t = 0; t < 9; ++t) {
        if (nbr[t] < 0) continue;
        const float4* hp = reinterpret_cast<const float4*>(hfeat + (size_t)nbr[t] * CH);
        const float a = e[t] * inv;
        #pragma unroll
        for (int k = 0; k < CH / 4; ++k) {
            float4 v = hp[k];
            acc[4*k]   = fmaf(a, v.x, acc[4*k]);
            acc[4*k+1] = fmaf(a, v.y, acc[4*k+1]);
            acc[4*k+2] = fmaf(a, v.z, acc[4*k+2]);
            acc[4*k+3] = fmaf(a, v.w, acc[4*k+3]);
        }
    }

    float* ob = out + ((size_t)b * CH * (HGT * WID)) + (size_t)i * WID + j;
    #pragma unroll
    for (int co = 0; co < CH; ++co)
        ob[(size_t)co * (HGT * WID)] = acc[co] + bias[co];
}

// ---------------------------------------------------------------------------
extern "C" void kernel_launch(void* const* d_in, const int* in_sizes, int n_in,
                              void* d_out, int out_size, void* d_ws, size_t ws_size,
                              hipStream_t stream) {
    const float* x       = (const float*)d_in[0];
    const float* pos_w   = (const float*)d_in[1];
    const float* pos_b   = (const float*)d_in[2];
    const float* lin_w   = (const float*)d_in[3];
    const float* att_src = (const float*)d_in[4];
    const float* att_dst = (const float*)d_in[5];
    const float* bias    = (const float*)d_in[6];
    // edge_src / edge_dst (d_in[7], d_in[8]) are implied by the fixed grid topology.

    float* out   = (float*)d_out;
    float* hfeat = (float*)d_ws;                       // NODES*64 f32 = 33.5 MB
    float* asrc  = hfeat + (size_t)NODES * CH;         // NODES f32
    float* adst  = asrc + NODES;                       // NODES f32

    gat_feat<<<dim3(NB * HGT), dim3(WID), 0, stream>>>(
        x, pos_w, pos_b, lin_w, att_src, att_dst, hfeat, asrc, adst);
    gat_aggr<<<dim3(NB * HGT), dim3(WID), 0, stream>>>(
        hfeat, asrc, adst, bias, out);
}

// Round 2
// 137.116 us; speedup vs baseline: 1.2219x; 1.2219x over previous
//
#include <hip/hip_runtime.h>

// Problem constants
#define HGT 256
#define WID 256
#define CH  64
#define NB  2
#define HW  (HGT * WID)
#define NODES (NB * HW)
#define NEG_SLOPE 0.2f

// ---------------------------------------------------------------------------
// Kernel A: hfeat = (x + pe) @ lin_w (planar [b][c][h][w] output),
//           a_src = hfeat@att_src, a_dst = hfeat@att_dst.
// Block = 256 threads = 64 pixels (tx) x 4 co-groups of 16 channels (ty).
// Grid = 2048 blocks -> 32 waves/CU demand; ~40 VGPR -> high occupancy.
// Weight rows read via scalar (readfirstlane-uniform) base -> s_load_dwordx16.
// ---------------------------------------------------------------------------
__global__ __launch_bounds__(256) void gat_feat(
    const float* __restrict__ x, const float* __restrict__ pos_w,
    const float* __restrict__ pos_b, const float* __restrict__ lin_w,
    const float* __restrict__ att_src, const float* __restrict__ att_dst,
    float* __restrict__ hfeat, float* __restrict__ asrc, float* __restrict__ adst)
{
    __shared__ float W0[CH], W1[CH], Bc[CH];
    __shared__ float red_s[4][64], red_d[4][64];

    const int tid = threadIdx.x;
    const int tx  = tid & 63;          // pixel within 64-px chunk
    const int ty  = tid >> 6;          // co-group 0..3

    const int bid   = blockIdx.x;      // 0..2047
    const int chunk = bid & 3;
    const int bi    = bid >> 2;        // b*256 + i
    const int i     = bi & (HGT - 1);
    const int b     = bi >> 8;
    const int j     = chunk * 64 + tx;

    // pe @ lin_w decomposes to py*W0 + px*W1 + Bc (rank-2 + const) per co.
    if (tid < CH) {
        float w0 = 0.f, w1 = 0.f, bc = 0.f;
        for (int ci = 0; ci < CH; ++ci) {
            float lwv = lin_w[ci * CH + tid];
            w0 = fmaf(pos_w[ci],      lwv, w0);   // pos_w[0, ci]
            w1 = fmaf(pos_w[CH + ci], lwv, w1);   // pos_w[1, ci]
            bc = fmaf(pos_b[ci],      lwv, bc);
        }
        W0[tid] = w0; W1[tid] = w1; Bc[tid] = bc;
    }
    __syncthreads();

    const int cob = __builtin_amdgcn_readfirstlane(ty) * 16;  // scalar co base

    float acc[16];
    #pragma unroll
    for (int k = 0; k < 16; ++k) acc[k] = 0.f;

    const float* xb = x + (size_t)b * CH * HW + (size_t)i * WID + j;
    const float* lw = lin_w + cob;     // uniform pointer -> scalar loads
    #pragma unroll 8
    for (int ci = 0; ci < CH; ++ci) {
        float xv = xb[(size_t)ci * HW];
        #pragma unroll
        for (int k = 0; k < 16; ++k)
            acc[k] = fmaf(xv, lw[ci * CH + k], acc[k]);
    }

    const float py = -1.f + (2.f / 255.f) * (float)i;
    const float px = -1.f + (2.f / 255.f) * (float)j;

    float as = 0.f, ad = 0.f;
    float* hb = hfeat + ((size_t)b * CH + cob) * HW + (size_t)i * WID + j;
    #pragma unroll
    for (int k = 0; k < 16; ++k) {
        const int co = cob + k;
        float h = acc[k] + py * W0[co] + px * W1[co] + Bc[co];
        hb[(size_t)k * HW] = h;                      // coalesced 256B/wave
        as = fmaf(h, att_src[co], as);
        ad = fmaf(h, att_dst[co], ad);
    }

    // reduce a_src/a_dst partials across the 4 co-groups
    red_s[ty][tx] = as; red_d[ty][tx] = ad;
    __syncthreads();
    if (ty == 0) {
        const size_t node = (size_t)bi * WID + j;    // b*HW + i*WID + j
        asrc[node] = red_s[0][tx] + red_s[1][tx] + red_s[2][tx] + red_s[3][tx];
        adst[node] = red_d[0][tx] + red_d[1][tx] + red_d[2][tx] + red_d[3][tx];
    }
}

// ---------------------------------------------------------------------------
// Kernel B: per destination pixel, softmax over <=9 valid taps, then
// out[b,co,i,j] = sum_t alpha_t * hfeat[b,co,i+dr,j+dc] + bias[co].
// Same 64px x 4-co-group block shape. Bijective XCD swizzle gives each XCD a
// contiguous band of image rows -> hfeat row reuse hits L2 instead of HBM.
// ---------------------------------------------------------------------------
__global__ __launch_bounds__(256) void gat_aggr(
    const float* __restrict__ hfeat, const float* __restrict__ asrc,
    const float* __restrict__ adst, const float* __restrict__ bias,
    float* __restrict__ out)
{
    const int tid = threadIdx.x;
    const int tx  = tid & 63;
    const int ty  = tid >> 6;

    // nwg = 2048, divisible by 8 XCDs: xcd k owns contiguous work ids [k*256, k*256+256)
    const int raw = blockIdx.x;
    const int wg  = (raw & 7) * 256 + (raw >> 3);

    const int chunk = wg & 3;
    const int bi    = wg >> 2;         // b*256 + i
    const int i     = bi & (HGT - 1);
    const int b     = bi >> 8;
    const int j     = chunk * 64 + tx;
    const int node  = bi * WID + j;    // b*HW + i*WID + j

    const float adv = adst[node];

    float w[9];
    int   off[9];
    float m = -1e30f;
    #pragma unroll
    for (int t = 0; t < 9; ++t) {
        const int dr = t / 3 - 1, dc = t % 3 - 1;
        const int r = i + dr, c = j + dc;
        const bool ok = (r >= 0) && (r < HGT) && (c >= 0) && (c < WID);
        off[t] = ok ? (dr * WID + dc) : 0;           // clamped -> always in-bounds
        float ev = -1e30f;
        if (ok) {
            ev = asrc[node + off[t]] + adv;
            ev = (ev >= 0.f) ? ev : NEG_SLOPE * ev;
        }
        w[t] = ev;
        m = fmaxf(m, ev);
    }

    float s = 0.f;
    #pragma unroll
    for (int t = 0; t < 9; ++t) {
        float p = (w[t] > -1e29f) ? __expf(w[t] - m) : 0.f;
        w[t] = p; s += p;
    }
    const float inv = 1.f / s;
    #pragma unroll
    for (int t = 0; t < 9; ++t) w[t] *= inv;

    const int cob = __builtin_amdgcn_readfirstlane(ty) * 16;
    const float* hb = hfeat + ((size_t)b * CH + cob) * HW + (size_t)i * WID + j;
    float*       ob = out   + ((size_t)b * CH + cob) * HW + (size_t)i * WID + j;

    float acc[16];
    #pragma unroll
    for (int k = 0; k < 16; ++k) acc[k] = 0.f;

    #pragma unroll
    for (int t = 0; t < 9; ++t) {
        const float* hp = hb + off[t];
        const float  a  = w[t];
        #pragma unroll
        for (int k = 0; k < 16; ++k)
            acc[k] = fmaf(a, hp[(size_t)k * HW], acc[k]);   // coalesced 256B/wave
    }

    #pragma unroll
    for (int k = 0; k < 16; ++k)
        ob[(size_t)k * HW] = acc[k] + bias[cob + k];
}

// ---------------------------------------------------------------------------
extern "C" void kernel_launch(void* const* d_in, const int* in_sizes, int n_in,
                              void* d_out, int out_size, void* d_ws, size_t ws_size,
                              hipStream_t stream) {
    const float* x       = (const float*)d_in[0];
    const float* pos_w   = (const float*)d_in[1];
    const float* pos_b   = (const float*)d_in[2];
    const float* lin_w   = (const float*)d_in[3];
    const float* att_src = (const float*)d_in[4];
    const float* att_dst = (const float*)d_in[5];
    const float* bias    = (const float*)d_in[6];
    // edge_src / edge_dst (d_in[7], d_in[8]) are implied by the fixed grid topology.

    float* out   = (float*)d_out;
    float* hfeat = (float*)d_ws;                       // NODES*64 f32, planar [b][c][h][w]
    float* asrc  = hfeat + (size_t)NODES * CH;         // NODES f32
    float* adst  = asrc + NODES;                       // NODES f32

    gat_feat<<<dim3(2048), dim3(256), 0, stream>>>(
        x, pos_w, pos_b, lin_w, att_src, att_dst, hfeat, asrc, adst);
    gat_aggr<<<dim3(2048), dim3(256), 0, stream>>>(
        hfeat, asrc, adst, bias, out);
}